// Round 2
// baseline (270.623 us; speedup 1.0000x reference)
//
#include <hip/hip_runtime.h>
#include <hip/hip_bf16.h>
#include <stdint.h>

#define BB 2
#define SS 2048
#define DD 1024
#define HH 16
#define HDIM 64
#define MM (BB*SS)   // 4096

typedef __attribute__((ext_vector_type(4))) float f32x4;
typedef __attribute__((ext_vector_type(8))) short short8;
typedef __attribute__((ext_vector_type(8))) unsigned short ushort8;
typedef unsigned short ushort_t;

__device__ __forceinline__ ushort_t f2bf(float f) {
    union { float f; unsigned u; } v; v.f = f;
    unsigned r = v.u + 0x7FFF + ((v.u >> 16) & 1);   // RNE
    return (ushort_t)(r >> 16);
}

__device__ __forceinline__ void gload_lds16(const void* g, void* lds_base, unsigned lds_byte_off) {
    auto l = (__attribute__((address_space(3))) unsigned*)((char*)lds_base + lds_byte_off);
    auto p = (const __attribute__((address_space(1))) unsigned*)g;
    __builtin_amdgcn_global_load_lds(p, l, 16, 0, 0);
}

// ---------------- fp32 -> bf16 conversion (vectorized, 8 elems/thread) --------
__global__ __launch_bounds__(256) void cvt_kernel(const float* __restrict__ src,
                                                  ushort_t* __restrict__ dst, int n8) {
    int i = blockIdx.x * 256 + threadIdx.x;
    if (i >= n8) return;
    const float4* s = (const float4*)src;
    float4 a = s[2*i], b = s[2*i+1];
    ushort8 o;
    o[0]=f2bf(a.x); o[1]=f2bf(a.y); o[2]=f2bf(a.z); o[3]=f2bf(a.w);
    o[4]=f2bf(b.x); o[5]=f2bf(b.y); o[6]=f2bf(b.z); o[7]=f2bf(b.w);
    *(ushort8*)(dst + (size_t)i*8) = o;
}

// ---------------- GEMM: C[M][N] = A[M][K] * Bw[N][K]^T  (all bf16 in) --------
// 128x128 tile, BK=32, 256 threads = 4 waves (2x2 of 64x64).
// LDS tiles [128 rows][32 bf16 = 64B]: read-swizzle chunkslot ^= (row>>1)&3,
// staged with pre-swizzled GLOBAL source so LDS dest stays linear (rule 21).
__global__ __launch_bounds__(256) void gemm128(const ushort_t* __restrict__ A,
                                               const ushort_t* __restrict__ Bw,
                                               ushort_t* __restrict__ Cb,   // bf16 out (or null)
                                               float* __restrict__ Cf,      // f32 out (or null)
                                               const float* __restrict__ bias,
                                               int Mdim, int Ndim, int Kdim) {
    __shared__ ushort_t As[128*32];
    __shared__ ushort_t Bs[128*32];
    const int tid = threadIdx.x;
    const int lane = tid & 63;
    const int wv = tid >> 6;
    const int wr = (wv >> 1) * 64, wc = (wv & 1) * 64;
    const int l16 = lane & 15, kg = lane >> 4;
    const int brow = blockIdx.y * 128;
    const int bcol = blockIdx.x * 128;

    f32x4 acc[4][4];
#pragma unroll
    for (int i = 0; i < 4; i++)
#pragma unroll
        for (int j = 0; j < 4; j++) acc[i][j] = (f32x4){0.f,0.f,0.f,0.f};

    // staging: 512 16B-chunks per tile; thread covers chunks tid and tid+256
    const int c0 = tid, c1 = tid + 256;
    const int ar0 = c0 >> 2, sl0 = (c0 & 3) ^ ((ar0 >> 1) & 3);
    const int ar1 = c1 >> 2, sl1 = (c1 & 3) ^ ((ar1 >> 1) & 3);
    const ushort_t* Ag0 = A + (size_t)(brow + ar0) * Kdim + sl0 * 8;
    const ushort_t* Ag1 = A + (size_t)(brow + ar1) * Kdim + sl1 * 8;
    const ushort_t* Bg0 = Bw + (size_t)(bcol + ar0) * Kdim + sl0 * 8;
    const ushort_t* Bg1 = Bw + (size_t)(bcol + ar1) * Kdim + sl1 * 8;

    for (int k0 = 0; k0 < Kdim; k0 += 32) {
        __syncthreads();
        gload_lds16(Ag0 + k0, As, c0 * 16);
        gload_lds16(Ag1 + k0, As, c1 * 16);
        gload_lds16(Bg0 + k0, Bs, c0 * 16);
        gload_lds16(Bg1 + k0, Bs, c1 * 16);
        __syncthreads();

        short8 af[4], bf[4];
#pragma unroll
        for (int mi = 0; mi < 4; mi++) {
            int row = wr + mi * 16 + l16;
            af[mi] = *(const short8*)((const char*)As + row * 64 + ((kg ^ ((row >> 1) & 3)) * 16));
        }
#pragma unroll
        for (int ni = 0; ni < 4; ni++) {
            int row = wc + ni * 16 + l16;
            bf[ni] = *(const short8*)((const char*)Bs + row * 64 + ((kg ^ ((row >> 1) & 3)) * 16));
        }
#pragma unroll
        for (int mi = 0; mi < 4; mi++)
#pragma unroll
            for (int ni = 0; ni < 4; ni++)
                acc[mi][ni] = __builtin_amdgcn_mfma_f32_16x16x32_bf16(af[mi], bf[ni], acc[mi][ni], 0, 0, 0);
    }

    // epilogue: D layout col=lane&15, row=(lane>>4)*4+reg
    if (Cb) {
#pragma unroll
        for (int mi = 0; mi < 4; mi++)
#pragma unroll
            for (int ni = 0; ni < 4; ni++) {
                int row = brow + wr + mi * 16 + kg * 4;
                int col = bcol + wc + ni * 16 + l16;
#pragma unroll
                for (int r = 0; r < 4; r++)
                    Cb[(size_t)(row + r) * Ndim + col] = f2bf(acc[mi][ni][r]);
            }
    } else {
#pragma unroll
        for (int mi = 0; mi < 4; mi++)
#pragma unroll
            for (int ni = 0; ni < 4; ni++) {
                int row = brow + wr + mi * 16 + kg * 4;
                int col = bcol + wc + ni * 16 + l16;
                float bv = bias ? bias[col] : 0.f;
#pragma unroll
                for (int r = 0; r < 4; r++)
                    Cf[(size_t)(row + r) * Ndim + col] = acc[mi][ni][r] + bv;
            }
    }
}

// ---------------- V transpose: qkv v-part -> vT[bh][hd][s] -------------------
__global__ __launch_bounds__(256) void transv(const ushort_t* __restrict__ qkv,
                                              ushort_t* __restrict__ vT) {
    int bh = blockIdx.y;
    int b = bh >> 4, h = bh & 15;
    int s0 = blockIdx.x * 64;
    __shared__ ushort_t t[64][72];
    int tid = threadIdx.x;
    int sr = tid >> 2, cb = (tid & 3) * 16;
    const ushort_t* src = qkv + (size_t)(b * SS + s0 + sr) * 3072 + 2048 + h * 64 + cb;
    ushort8 v0 = *(const ushort8*)src;
    ushort8 v1 = *(const ushort8*)(src + 8);
#pragma unroll
    for (int i = 0; i < 8; i++) t[sr][cb + i] = v0[i];
#pragma unroll
    for (int i = 0; i < 8; i++) t[sr][cb + 8 + i] = v1[i];
    __syncthreads();
    int hd = tid >> 2, sb = (tid & 3) * 16;
    ushort_t* dst = vT + ((size_t)bh * 64 + hd) * SS + s0 + sb;
    ushort8 o0, o1;
#pragma unroll
    for (int i = 0; i < 8; i++) o0[i] = t[sb + i][hd];
#pragma unroll
    for (int i = 0; i < 8; i++) o1[i] = t[sb + 8 + i][hd];
    *(ushort8*)dst = o0;
    *(ushort8*)(dst + 8) = o1;
}

// ---------------- flash attention: 64 q-rows/block, KB=64, 4 waves -----------
__global__ __launch_bounds__(256) void attn64(const ushort_t* __restrict__ qkv,
                                              const ushort_t* __restrict__ vT,
                                              ushort_t* __restrict__ ctx) {
    int bh = blockIdx.y;
    int b = bh >> 4, h = bh & 15;
    int q0 = blockIdx.x * 64;
    __shared__ ushort_t Ks[64 * 64];     // [krow][hd], row=128B, XOR-swizzled
    __shared__ ushort_t Vs[64 * 64];     // [hd][k],   row=128B, XOR-swizzled
    __shared__ ushort_t Ps[4][16 * 64];  // per-wave P, row=128B, XOR-swizzled
    int tid = threadIdx.x, lane = tid & 63, wv = tid >> 6;
    int l16 = lane & 15, kg = lane >> 4;

    // Q fragments (A-operand, direct from global; scale folded into scores later)
    const ushort_t* qp = qkv + (size_t)(b * SS + q0 + wv * 16 + l16) * 3072 + h * 64 + kg * 8;
    short8 qf0 = *(const short8*)qp;
    short8 qf1 = *(const short8*)(qp + 32);

    // staging: 512 chunks per 64x128B tile
    const int c0 = tid, c1 = tid + 256;
    const int kr0 = c0 >> 3, sl0 = (c0 & 7) ^ (kr0 & 7);
    const int kr1 = c1 >> 3, sl1 = (c1 & 7) ^ (kr1 & 7);
    const ushort_t* Kg0 = qkv + (size_t)(b * SS + kr0) * 3072 + 1024 + h * 64 + sl0 * 8;
    const ushort_t* Kg1 = qkv + (size_t)(b * SS + kr1) * 3072 + 1024 + h * 64 + sl1 * 8;
    const ushort_t* Vg0 = vT + ((size_t)bh * 64 + kr0) * SS + sl0 * 8;
    const ushort_t* Vg1 = vT + ((size_t)bh * 64 + kr1) * SS + sl1 * 8;

    float mrun[4], lrun[4];
    f32x4 oacc[4];
#pragma unroll
    for (int r = 0; r < 4; r++) { mrun[r] = -1e30f; lrun[r] = 0.f; }
#pragma unroll
    for (int nf = 0; nf < 4; nf++) oacc[nf] = (f32x4){0.f,0.f,0.f,0.f};

    for (int kk = 0; kk < SS; kk += 64) {
        __syncthreads();
        gload_lds16(Kg0 + (size_t)kk * 3072, Ks, c0 * 16);
        gload_lds16(Kg1 + (size_t)kk * 3072, Ks, c1 * 16);
        gload_lds16(Vg0 + kk, Vs, c0 * 16);
        gload_lds16(Vg1 + kk, Vs, c1 * 16);
        __syncthreads();

        // S = Q K^T  (per wave: 16 q-rows x 64 k-cols)
        f32x4 sa[4];
#pragma unroll
        for (int nf = 0; nf < 4; nf++) {
            sa[nf] = (f32x4){0.f,0.f,0.f,0.f};
            int row = nf * 16 + l16;
            const char* base = (const char*)Ks + row * 128;
            short8 kfa = *(const short8*)(base + ((kg * 16) ^ ((row & 7) << 4)));
            short8 kfb = *(const short8*)(base + ((64 + kg * 16) ^ ((row & 7) << 4)));
            sa[nf] = __builtin_amdgcn_mfma_f32_16x16x32_bf16(qf0, kfa, sa[nf], 0, 0, 0);
            sa[nf] = __builtin_amdgcn_mfma_f32_16x16x32_bf16(qf1, kfb, sa[nf], 0, 0, 0);
        }

        // online softmax (rows kg*4+r; reductions within 16-lane groups)
        float p[4][4], mnew[4], corr[4];
#pragma unroll
        for (int r = 0; r < 4; r++) {
            float mx = fmaxf(fmaxf(sa[0][r], sa[1][r]), fmaxf(sa[2][r], sa[3][r]));
            mx = fmaxf(mx, __shfl_xor(mx, 1));
            mx = fmaxf(mx, __shfl_xor(mx, 2));
            mx = fmaxf(mx, __shfl_xor(mx, 4));
            mx = fmaxf(mx, __shfl_xor(mx, 8));
            mx *= 0.125f;
            mnew[r] = fmaxf(mrun[r], mx);
            corr[r] = __expf(mrun[r] - mnew[r]);
            mrun[r] = mnew[r];
        }
#pragma unroll
        for (int nf = 0; nf < 4; nf++)
#pragma unroll
            for (int r = 0; r < 4; r++)
                p[nf][r] = __expf(sa[nf][r] * 0.125f - mnew[r]);
#pragma unroll
        for (int r = 0; r < 4; r++) {
            float s = p[0][r] + p[1][r] + p[2][r] + p[3][r];
            s += __shfl_xor(s, 1);
            s += __shfl_xor(s, 2);
            s += __shfl_xor(s, 4);
            s += __shfl_xor(s, 8);
            lrun[r] = lrun[r] * corr[r] + s;
        }
#pragma unroll
        for (int nf = 0; nf < 4; nf++) {
            f32x4 o = oacc[nf];
            o[0] *= corr[0]; o[1] *= corr[1]; o[2] *= corr[2]; o[3] *= corr[3];
            oacc[nf] = o;
        }

        // P -> LDS (bf16, swizzled), per-wave private
        ushort_t* pb = Ps[wv];
#pragma unroll
        for (int r = 0; r < 4; r++) {
            int row = kg * 4 + r;
            char* base = (char*)pb + row * 128;
#pragma unroll
            for (int nf = 0; nf < 4; nf++)
                *(ushort_t*)(base + ((nf * 32 + l16 * 2) ^ ((row & 7) << 4))) = f2bf(p[nf][r]);
        }

        // O += P V
#pragma unroll
        for (int ks = 0; ks < 2; ks++) {
            short8 pa = *(const short8*)((const char*)pb + l16 * 128 +
                                         ((ks * 64 + kg * 16) ^ ((l16 & 7) << 4)));
#pragma unroll
            for (int nf = 0; nf < 4; nf++) {
                int vrow = nf * 16 + l16;
                short8 vf = *(const short8*)((const char*)Vs + vrow * 128 +
                                             ((ks * 64 + kg * 16) ^ ((vrow & 7) << 4)));
                oacc[nf] = __builtin_amdgcn_mfma_f32_16x16x32_bf16(pa, vf, oacc[nf], 0, 0, 0);
            }
        }
    }

    // epilogue: ctx[b, q, h*64+hd] bf16
#pragma unroll
    for (int nf = 0; nf < 4; nf++)
#pragma unroll
        for (int r = 0; r < 4; r++) {
            int row = b * SS + q0 + wv * 16 + kg * 4 + r;
            float val = oacc[nf][r] / lrun[r];
            ctx[(size_t)row * DD + h * 64 + nf * 16 + l16] = f2bf(val);
        }
}

extern "C" void kernel_launch(void* const* d_in, const int* in_sizes, int n_in,
                              void* d_out, int out_size, void* d_ws, size_t ws_size,
                              hipStream_t stream) {
    const float* x  = (const float*)d_in[0];
    const float* Wq = (const float*)d_in[1];
    const float* Wk = (const float*)d_in[2];
    const float* Wv = (const float*)d_in[3];
    const float* Wo = (const float*)d_in[4];
    const float* bo = (const float*)d_in[5];
    float* out = (float*)d_out;

    char* ws = (char*)d_ws;
    ushort_t* xb   = (ushort_t*)(ws);                       // 8 MB  [4096][1024]
    ushort_t* Wqkv = (ushort_t*)(ws + (8ull  << 20));       // 6 MB  [3072][1024]
    ushort_t* Wob  = (ushort_t*)(ws + (14ull << 20));       // 2 MB  [1024][1024]
    ushort_t* qkv  = (ushort_t*)(ws + (16ull << 20));       // 24 MB [4096][3072]
    ushort_t* vT   = (ushort_t*)(ws + (40ull << 20));       // 8 MB  [32][64][2048]
    ushort_t* ctx  = (ushort_t*)(ws + (48ull << 20));       // 8 MB  [4096][1024]

    const int n8x = MM * DD / 8;   // 524288
    const int n8w = DD * DD / 8;   // 131072
    cvt_kernel<<<n8x / 256, 256, 0, stream>>>(x, xb, n8x);
    cvt_kernel<<<n8w / 256, 256, 0, stream>>>(Wq, Wqkv,                 n8w);
    cvt_kernel<<<n8w / 256, 256, 0, stream>>>(Wk, Wqkv + (size_t)DD*DD, n8w);
    cvt_kernel<<<n8w / 256, 256, 0, stream>>>(Wv, Wqkv + (size_t)2*DD*DD, n8w);
    cvt_kernel<<<n8w / 256, 256, 0, stream>>>(Wo, Wob, n8w);

    // QKV projection: [4096][1024] x [3072][1024]^T -> qkv bf16
    gemm128<<<dim3(3072 / 128, MM / 128), 256, 0, stream>>>(xb, Wqkv, qkv, nullptr, nullptr,
                                                            MM, 3072, DD);
    transv<<<dim3(SS / 64, BB * HH), 256, 0, stream>>>(qkv, vT);
    attn64<<<dim3(SS / 64, BB * HH), 256, 0, stream>>>(qkv, vT, ctx);
    // output projection: ctx x Wo^T + bo -> out fp32
    gemm128<<<dim3(DD / 128, MM / 128), 256, 0, stream>>>(ctx, Wob, nullptr, out, bo,
                                                          MM, DD, DD);
}